// Round 10
// baseline (73.166 us; speedup 1.0000x reference)
//
#include <hip/hip_runtime.h>
#include <math.h>

namespace {
constexpr int NB = 2048;      // batch
constexpr int NNODE = 6;      // nodes
constexpr int DD = 2048;      // feature dim
constexpr int HH = 1024;      // hidden
constexpr int CC = 200;       // classes
constexpr int K2 = 2 * DD;    // 4096 (concat dim)
constexpr int NPAD = 256;     // padded class dim
constexpr int ZS1 = 4;        // split-K for g1 (K per z = 256)
constexpr int ZS2 = 16;       // split-K for gemm2 (K per z = 256)
constexpr float ALPHA_C = 0.015f;
constexpr float SCALE_C = 24.0f;

constexpr int G1_BLOCKS = (K2 / 32) * ZS1;   // 512
constexpr int PQ_BLOCKS = 1024;              // persistent, grid-stride 2 b each
}

typedef __attribute__((ext_vector_type(8))) short bf16x8;
typedef __attribute__((ext_vector_type(4))) float f32x4;

static __device__ __forceinline__ unsigned short f2bf(float x) {
    union { float f; unsigned int u; } v; v.f = x;
    unsigned int r = v.u + 0x7FFFu + ((v.u >> 16) & 1u);  // RNE
    return (unsigned short)(r >> 16);
}

static __device__ __forceinline__ float bf2f(unsigned short u) {
    union { unsigned int i; float f; } v; v.i = ((unsigned int)u) << 16;
    return v.f;
}

static __device__ __forceinline__ unsigned pack2(float a, float b) {
    return (unsigned)f2bf(a) | ((unsigned)f2bf(b) << 16);
}

// ---------------------------------------------------------------------------
// Wave-parallel node weights (lane u*8+v computes one exp+sqrt); lane v==0
// holds s[u] after the 8-lane row reduce.
// ---------------------------------------------------------------------------
static __device__ __forceinline__ float compute_s_lane(const float* __restrict__ cdds,
                                                       int b, int* u_out) {
    const int lane = threadIdx.x & 63;
    const int u = lane >> 3;      // 0..7
    const int v = lane & 7;       // 0..7
    *u_out = u;
    const float* cd = cdds + (size_t)b * 36;
    float w = 0.f;
    const bool valid = (u < 6) & (v < 6) & (u != v);
    if (u < 6 && v < 6 && u != v) {
        float cyu = (cd[u * 6 + 1] + cd[u * 6 + 3]) * 0.5f;
        float cxu = (cd[u * 6 + 2] + cd[u * 6 + 4]) * 0.5f;
        float cyv = (cd[v * 6 + 1] + cd[v * 6 + 3]) * 0.5f;
        float cxv = (cd[v * 6 + 2] + cd[v * 6 + 4]) * 0.5f;
        float dx = cxu - cxv, dy = cyu - cyv;
        w = expf(-ALPHA_C * sqrtf(dx * dx + dy * dy));
    }
    float s = w;
#pragma unroll
    for (int m = 32; m >= 1; m >>= 1) s += __shfl_xor(s, m);
    float mean = s * (1.f / 30.f);
    float tt = valid ? fmaxf(w - mean, 0.f) : 0.f;
    tt += __shfl_xor(tt, 1);
    tt += __shfl_xor(tt, 2);
    tt += __shfl_xor(tt, 4);
    return SCALE_C * tt * 0.2f;   // s[u] for this lane's row u
}

// ---------------------------------------------------------------------------
// k_small: blocks [0,64):   cls_w -> cls_wT bf16 [256][1024] (transposed,pad)
//          blocks [64,89):  bvec[c] = fc_b @ cls_w + cls_b
//          blocks [89,601): sbuf[b][u] node weights (one b per wave)
// ---------------------------------------------------------------------------
__global__ __launch_bounds__(256) void k_small(const float* __restrict__ cls_w,
                                               const float* __restrict__ fc_b,
                                               const float* __restrict__ cls_b,
                                               const float* __restrict__ cdds,
                                               unsigned short* __restrict__ cls_wT,
                                               float* __restrict__ bvec,
                                               float* __restrict__ sbuf)
{
    __shared__ float sm[64 * 65];
    const int bx = blockIdx.x;
    const int t = threadIdx.x;
    if (bx >= 89) {
        // ---- node weights: 4 waves, one b each
        const int b = (bx - 89) * 4 + (t >> 6);
        int u;
        float su = compute_s_lane(cdds, b, &u);
        if ((t & 7) == 0 && u < 6) sbuf[b * 6 + u] = su;
        return;
    }
    if (bx >= 64) {
        const int bb = bx - 64;           // 0..24
        float* red = sm;
        int c8 = t & 7;
        int hs = t >> 3;
        int c = bb * 8 + c8;              // < 200
        float acc = 0.f;
        for (int h = hs; h < HH; h += 32)
            acc += fc_b[h] * cls_w[(size_t)h * CC + c];
        red[t] = acc;
        __syncthreads();
        for (int s = 128; s >= 8; s >>= 1) {
            if (t < s) red[t] += red[t + s];
            __syncthreads();
        }
        if (t < 8) bvec[c] = red[t] + cls_b[c];
        return;
    }
    const int kt = bx & 15;
    const int nt = bx >> 4;
#pragma unroll
    for (int c = 0; c < 4; ++c) {
        int i = t + c * 256;
        int kr = i >> 4;
        int n4 = (i & 15) << 2;
        int gn = nt * 64 + n4;
        const float* sp = cls_w + (size_t)(kt * 64 + kr) * CC + gn;
        float4 v = {0.f, 0.f, 0.f, 0.f};
        if (gn + 3 < CC) {
            v = *(const float4*)sp;
        } else {
            if (gn + 0 < CC) v.x = sp[0];
            if (gn + 1 < CC) v.y = sp[1];
            if (gn + 2 < CC) v.z = sp[2];
            if (gn + 3 < CC) v.w = sp[3];
        }
        sm[kr * 65 + n4 + 0] = v.x; sm[kr * 65 + n4 + 1] = v.y;
        sm[kr * 65 + n4 + 2] = v.z; sm[kr * 65 + n4 + 3] = v.w;
    }
    __syncthreads();
#pragma unroll
    for (int c = 0; c < 4; ++c) {
        int i = t + c * 256;
        int nr = i >> 4;
        int k4 = (i & 15) << 2;
        ushort4 o;
        o.x = f2bf(sm[(k4 + 0) * 65 + nr]);
        o.y = f2bf(sm[(k4 + 1) * 65 + nr]);
        o.z = f2bf(sm[(k4 + 2) * 65 + nr]);
        o.w = f2bf(sm[(k4 + 3) * 65 + nr]);
        *(ushort4*)(cls_wT + (size_t)(nt * 64 + nr) * HH + kt * 64 + k4) = o;
    }
}

// ---------------------------------------------------------------------------
// k_mid: blocks [0,512):     g1 partM[z][4096][256] = fc_w @ cls_w (split-4)
//        blocks [512,1536):  pq via PERSISTENT grid-stride blocks (2 b each):
//                            pq[b][0:D]=sum_u s*pf, pq[b][D:2D]=sum_u pf
// 1536 blocks total -> blocks long-lived, dispatch cost amortized.
// ---------------------------------------------------------------------------
__global__ __launch_bounds__(256) void k_mid(const float* __restrict__ pf,
                                             const float* __restrict__ sbuf,
                                             const float* __restrict__ fc_w,
                                             const unsigned short* __restrict__ Bt,
                                             unsigned short* __restrict__ pq,
                                             float* __restrict__ partM)
{
    __shared__ short As[32][72];
    __shared__ short Bs[256][72];
    const int bx = blockIdx.x;
    const int t = threadIdx.x;

    if (bx >= G1_BLOCKS) {
        // ---------------- persistent pq streaming ----------------
        const int d = t << 3;   // 8 floats per thread (covers full D)
        for (int b = bx - G1_BLOCKS; b < NB; b += PQ_BLOCKS) {
            const float* base = pf + (size_t)b * NNODE * DD + d;
            float4 a00 = *(const float4*)(base + 0 * DD);
            float4 a01 = *(const float4*)(base + 0 * DD + 4);
            float4 a10 = *(const float4*)(base + 1 * DD);
            float4 a11 = *(const float4*)(base + 1 * DD + 4);
            float4 a20 = *(const float4*)(base + 2 * DD);
            float4 a21 = *(const float4*)(base + 2 * DD + 4);
            float4 a30 = *(const float4*)(base + 3 * DD);
            float4 a31 = *(const float4*)(base + 3 * DD + 4);
            float4 a40 = *(const float4*)(base + 4 * DD);
            float4 a41 = *(const float4*)(base + 4 * DD + 4);
            float4 a50 = *(const float4*)(base + 5 * DD);
            float4 a51 = *(const float4*)(base + 5 * DD + 4);
            float s0 = sbuf[b * 6 + 0], s1 = sbuf[b * 6 + 1];
            float s2 = sbuf[b * 6 + 2], s3 = sbuf[b * 6 + 3];
            float s4 = sbuf[b * 6 + 4], s5 = sbuf[b * 6 + 5];

            float4 q0, q1, p0 = {0, 0, 0, 0}, p1 = {0, 0, 0, 0};
            q0.x = a00.x + a10.x + a20.x + a30.x + a40.x + a50.x;
            q0.y = a00.y + a10.y + a20.y + a30.y + a40.y + a50.y;
            q0.z = a00.z + a10.z + a20.z + a30.z + a40.z + a50.z;
            q0.w = a00.w + a10.w + a20.w + a30.w + a40.w + a50.w;
            q1.x = a01.x + a11.x + a21.x + a31.x + a41.x + a51.x;
            q1.y = a01.y + a11.y + a21.y + a31.y + a41.y + a51.y;
            q1.z = a01.z + a11.z + a21.z + a31.z + a41.z + a51.z;
            q1.w = a01.w + a11.w + a21.w + a31.w + a41.w + a51.w;

            p0.x = fmaf(s0, a00.x, p0.x); p0.y = fmaf(s0, a00.y, p0.y);
            p0.z = fmaf(s0, a00.z, p0.z); p0.w = fmaf(s0, a00.w, p0.w);
            p1.x = fmaf(s0, a01.x, p1.x); p1.y = fmaf(s0, a01.y, p1.y);
            p1.z = fmaf(s0, a01.z, p1.z); p1.w = fmaf(s0, a01.w, p1.w);
            p0.x = fmaf(s1, a10.x, p0.x); p0.y = fmaf(s1, a10.y, p0.y);
            p0.z = fmaf(s1, a10.z, p0.z); p0.w = fmaf(s1, a10.w, p0.w);
            p1.x = fmaf(s1, a11.x, p1.x); p1.y = fmaf(s1, a11.y, p1.y);
            p1.z = fmaf(s1, a11.z, p1.z); p1.w = fmaf(s1, a11.w, p1.w);
            p0.x = fmaf(s2, a20.x, p0.x); p0.y = fmaf(s2, a20.y, p0.y);
            p0.z = fmaf(s2, a20.z, p0.z); p0.w = fmaf(s2, a20.w, p0.w);
            p1.x = fmaf(s2, a21.x, p1.x); p1.y = fmaf(s2, a21.y, p1.y);
            p1.z = fmaf(s2, a21.z, p1.z); p1.w = fmaf(s2, a21.w, p1.w);
            p0.x = fmaf(s3, a30.x, p0.x); p0.y = fmaf(s3, a30.y, p0.y);
            p0.z = fmaf(s3, a30.z, p0.z); p0.w = fmaf(s3, a30.w, p0.w);
            p1.x = fmaf(s3, a31.x, p1.x); p1.y = fmaf(s3, a31.y, p1.y);
            p1.z = fmaf(s3, a31.z, p1.z); p1.w = fmaf(s3, a31.w, p1.w);
            p0.x = fmaf(s4, a40.x, p0.x); p0.y = fmaf(s4, a40.y, p0.y);
            p0.z = fmaf(s4, a40.z, p0.z); p0.w = fmaf(s4, a40.w, p0.w);
            p1.x = fmaf(s4, a41.x, p1.x); p1.y = fmaf(s4, a41.y, p1.y);
            p1.z = fmaf(s4, a41.z, p1.z); p1.w = fmaf(s4, a41.w, p1.w);
            p0.x = fmaf(s5, a50.x, p0.x); p0.y = fmaf(s5, a50.y, p0.y);
            p0.z = fmaf(s5, a50.z, p0.z); p0.w = fmaf(s5, a50.w, p0.w);
            p1.x = fmaf(s5, a51.x, p1.x); p1.y = fmaf(s5, a51.y, p1.y);
            p1.z = fmaf(s5, a51.z, p1.z); p1.w = fmaf(s5, a51.w, p1.w);

            unsigned short* o = pq + (size_t)b * K2;
            uint4 po, qo;
            po.x = pack2(p0.x, p0.y); po.y = pack2(p0.z, p0.w);
            po.z = pack2(p1.x, p1.y); po.w = pack2(p1.z, p1.w);
            qo.x = pack2(q0.x, q0.y); qo.y = pack2(q0.z, q0.w);
            qo.z = pack2(q1.x, q1.y); qo.w = pack2(q1.z, q1.w);
            *(uint4*)(o + d) = po;
            *(uint4*)(o + DD + d) = qo;
        }
        return;
    }

    // ---------------- g1 ----------------
    const int lane = t & 63;
    const int wid = t >> 6;
    const int bm = (bx >> 2) * 32;
    const int z = bx & 3;
    const int kbase = z * (HH / ZS1);   // 256

    f32x4 acc[2][4] = {};

    for (int k0 = kbase; k0 < kbase + HH / ZS1; k0 += 64) {
#pragma unroll
        for (int c = 0; c < 2; ++c) {
            int i = t + c * 256;
            int row = i >> 4;              // 0..31
            int k4 = (i & 15) << 2;
            float4 v = *(const float4*)(fc_w + (size_t)(bm + row) * HH + k0 + k4);
            ushort4 o;
            o.x = f2bf(v.x); o.y = f2bf(v.y); o.z = f2bf(v.z); o.w = f2bf(v.w);
            *(ushort4*)&As[row][k4] = o;
        }
#pragma unroll
        for (int c = 0; c < 8; ++c) {
            int i = t + c * 256;
            int n = i >> 3;                // 0..255
            int k8 = (i & 7) << 3;
            *(uint4*)&Bs[n][k8] =
                *(const uint4*)(Bt + (size_t)n * HH + k0 + k8);
        }
        __syncthreads();
#pragma unroll
        for (int ks = 0; ks < 2; ++ks) {
            int kk = ks * 32 + ((lane >> 4) << 3);
            int ar = lane & 15;
            bf16x8 a0 = *(const bf16x8*)&As[ar][kk];
            bf16x8 a1 = *(const bf16x8*)&As[16 + ar][kk];
#pragma unroll
            for (int fn = 0; fn < 4; ++fn) {
                bf16x8 b = *(const bf16x8*)&Bs[wid * 64 + fn * 16 + ar][kk];
                acc[0][fn] = __builtin_amdgcn_mfma_f32_16x16x32_bf16(a0, b, acc[0][fn], 0, 0, 0);
                acc[1][fn] = __builtin_amdgcn_mfma_f32_16x16x32_bf16(a1, b, acc[1][fn], 0, 0, 0);
            }
        }
        __syncthreads();
    }
#pragma unroll
    for (int fm = 0; fm < 2; ++fm)
#pragma unroll
        for (int fn = 0; fn < 4; ++fn) {
            int gm0 = bm + fm * 16 + ((lane >> 4) << 2);
            int gn = wid * 64 + fn * 16 + (lane & 15);
#pragma unroll
            for (int r = 0; r < 4; ++r)
                partM[((size_t)z * K2 + gm0 + r) * NPAD + gn] = acc[fm][fn][r];
        }
}

// ---------------------------------------------------------------------------
// k_red: Mt[n][m] bf16 = sum_z partM[z][m][n] (64x64 LDS transpose tiles)
// ---------------------------------------------------------------------------
__global__ __launch_bounds__(256) void k_red(const float* __restrict__ partM,
                                             unsigned short* __restrict__ Mt)
{
    __shared__ float sm[64][69];
    const int bx = blockIdx.x;
    const int t = threadIdx.x;
    const int bm = (bx >> 2) * 64;        // m-tile (4096)
    const int bn = (bx & 3) * 64;         // n-tile (256)
#pragma unroll
    for (int c = 0; c < 4; ++c) {
        int i = t + c * 256;
        int mr = i >> 4;                  // 0..63
        int n4 = (i & 15) << 2;
        float4 s = {0.f, 0.f, 0.f, 0.f};
#pragma unroll
        for (int z = 0; z < ZS1; ++z) {
            float4 v = *(const float4*)(partM +
                ((size_t)z * K2 + bm + mr) * NPAD + bn + n4);
            s.x += v.x; s.y += v.y; s.z += v.z; s.w += v.w;
        }
        sm[mr][n4 + 0] = s.x; sm[mr][n4 + 1] = s.y;
        sm[mr][n4 + 2] = s.z; sm[mr][n4 + 3] = s.w;
    }
    __syncthreads();
#pragma unroll
    for (int c = 0; c < 4; ++c) {
        int i = t + c * 256;
        int nr = i >> 4;                  // 0..63
        int m4 = (i & 15) << 2;
        ushort4 o;
        o.x = f2bf(sm[m4 + 0][nr]);
        o.y = f2bf(sm[m4 + 1][nr]);
        o.z = f2bf(sm[m4 + 2][nr]);
        o.w = f2bf(sm[m4 + 3][nr]);
        *(ushort4*)(Mt + (size_t)(bn + nr) * K2 + bm + m4) = o;
    }
}

// ---------------------------------------------------------------------------
// GEMM2: part[z][2048][256] bf16 = pq @ Mt^T partial (split-K=16)
// grid (32, 16) = 512 blocks. Block 64m x 256n; wave tile 64m x 64n.
// ---------------------------------------------------------------------------
__global__ __launch_bounds__(256) void k_gemm2(const unsigned short* __restrict__ A,
                                               const unsigned short* __restrict__ Bt,
                                               unsigned short* __restrict__ part)
{
    __shared__ short As[64][72];    // 9.2 KB
    __shared__ short Bs[256][72];   // 36.9 KB
    const int t = threadIdx.x;
    const int lane = t & 63;
    const int wid = t >> 6;         // n-strip
    const int bm = blockIdx.x * 64;
    const int z = blockIdx.y;
    const int kbase = z * (K2 / ZS2);   // 256 per z

    f32x4 acc[4][4] = {};

    for (int k0 = kbase; k0 < kbase + K2 / ZS2; k0 += 64) {
#pragma unroll
        for (int c = 0; c < 2; ++c) {
            int i = t + c * 256;
            int row = i >> 3;
            int k8 = (i & 7) << 3;
            *(uint4*)&As[row][k8] =
                *(const uint4*)(A + (size_t)(bm + row) * K2 + k0 + k8);
        }
#pragma unroll
        for (int c = 0; c < 8; ++c) {
            int i = t + c * 256;
            int n = i >> 3;
            int k8 = (i & 7) << 3;
            *(uint4*)&Bs[n][k8] =
                *(const uint4*)(Bt + (size_t)n * K2 + k0 + k8);
        }
        __syncthreads();
#pragma unroll
        for (int ks = 0; ks < 2; ++ks) {
            int kk = ks * 32 + ((lane >> 4) << 3);
            int ar = lane & 15;
            bf16x8 a0 = *(const bf16x8*)&As[0 * 16 + ar][kk];
            bf16x8 a1 = *(const bf16x8*)&As[1 * 16 + ar][kk];
            bf16x8 a2 = *(const bf16x8*)&As[2 * 16 + ar][kk];
            bf16x8 a3 = *(const bf16x8*)&As[3 * 16 + ar][kk];
#pragma unroll
            for (int fn = 0; fn < 4; ++fn) {
                bf16x8 b = *(const bf16x8*)&Bs[wid * 64 + fn * 16 + ar][kk];
                acc[0][fn] = __builtin_amdgcn_mfma_f32_16x16x32_bf16(a0, b, acc[0][fn], 0, 0, 0);
                acc[1][fn] = __builtin_amdgcn_mfma_f32_16x16x32_bf16(a1, b, acc[1][fn], 0, 0, 0);
                acc[2][fn] = __builtin_amdgcn_mfma_f32_16x16x32_bf16(a2, b, acc[2][fn], 0, 0, 0);
                acc[3][fn] = __builtin_amdgcn_mfma_f32_16x16x32_bf16(a3, b, acc[3][fn], 0, 0, 0);
            }
        }
        __syncthreads();
    }
#pragma unroll
    for (int fm = 0; fm < 4; ++fm)
#pragma unroll
        for (int fn = 0; fn < 4; ++fn) {
            int gm0 = bm + fm * 16 + ((lane >> 4) << 2);
            int gn = wid * 64 + fn * 16 + (lane & 15);
#pragma unroll
            for (int r = 0; r < 4; ++r)
                part[((size_t)z * NB + gm0 + r) * NPAD + gn] = f2bf(acc[fm][fn][r]);
        }
}

// ---------------------------------------------------------------------------
// out[b,c0..c0+3] = (sum_z part[z][b][c]) / 6 + bvec[c]
// ---------------------------------------------------------------------------
__global__ __launch_bounds__(256) void k_combine(const unsigned short* __restrict__ part,
                                                 const float* __restrict__ bvec,
                                                 float* __restrict__ out)
{
    int idx = blockIdx.x * blockDim.x + threadIdx.x;   // NB * 50
    if (idx >= NB * (CC / 4)) return;
    int b = idx / (CC / 4);
    int c0 = (idx - b * (CC / 4)) << 2;
    float s0 = 0.f, s1 = 0.f, s2 = 0.f, s3 = 0.f;
#pragma unroll
    for (int z = 0; z < ZS2; ++z) {
        ushort4 v = *(const ushort4*)(part + ((size_t)z * NB + b) * NPAD + c0);
        s0 += bf2f(v.x); s1 += bf2f(v.y); s2 += bf2f(v.z); s3 += bf2f(v.w);
    }
    float4 o;
    o.x = s0 * (1.f / 6.f) + bvec[c0 + 0];
    o.y = s1 * (1.f / 6.f) + bvec[c0 + 1];
    o.z = s2 * (1.f / 6.f) + bvec[c0 + 2];
    o.w = s3 * (1.f / 6.f) + bvec[c0 + 3];
    *(float4*)(out + (size_t)b * CC + c0) = o;
}

// ---------------------------------------------------------------------------
extern "C" void kernel_launch(void* const* d_in, const int* in_sizes, int n_in,
                              void* d_out, int out_size, void* d_ws, size_t ws_size,
                              hipStream_t stream)
{
    const float* part_feats = (const float*)d_in[0];
    const float* cdds = (const float*)d_in[1];
    const float* fc_w = (const float*)d_in[2];   // (4096, 1024)
    const float* fc_b = (const float*)d_in[3];   // (1024,)
    const float* cls_w = (const float*)d_in[4];  // (1024, 200)
    const float* cls_b = (const float*)d_in[5];  // (200,)
    float* out = (float*)d_out;                  // (2048, 200)

    char* ws = (char*)d_ws;
    size_t off = 0;
    unsigned short* pq = (unsigned short*)(ws + off);     off += (size_t)NB * K2 * 2;         // 16.8 MB
    unsigned short* Mt = (unsigned short*)(ws + off);     off += (size_t)NPAD * K2 * 2;       // 2.1 MB
    unsigned short* cls_wT = (unsigned short*)(ws + off); off += (size_t)NPAD * HH * 2;       // 0.5 MB
    float* partM = (float*)(ws + off);                    off += (size_t)ZS1 * K2 * NPAD * 4; // 16.8 MB
    unsigned short* part = (unsigned short*)(ws + off);   off += (size_t)ZS2 * NB * NPAD * 2; // 16.8 MB
    float* bvec = (float*)(ws + off);                     off += 256 * 4;
    float* sbuf = (float*)(ws + off);                     off += (size_t)NB * NNODE * 4;

    // 1. cls_w -> cls_wT bf16 + bvec + node-weight table sbuf
    k_small<<<dim3(64 + 25 + NB / 4), dim3(256), 0, stream>>>(
        cls_w, fc_b, cls_b, cdds, cls_wT, bvec, sbuf);
    // 2. g1 (512 blocks) + PERSISTENT pq stream (1024 grid-stride blocks)
    k_mid<<<dim3(G1_BLOCKS + PQ_BLOCKS), dim3(256), 0, stream>>>(
        part_feats, sbuf, fc_w, cls_wT, pq, partM);
    // 3. reduce partM -> Mt bf16
    k_red<<<dim3(256), dim3(256), 0, stream>>>(partM, Mt);
    // 4. pq @ Mt^T partials (bf16), split-K=16
    k_gemm2<<<dim3(NB / 64, ZS2), dim3(256), 0, stream>>>(pq, Mt, part);
    // 5. combine + scale + bias
    k_combine<<<dim3((NB * (CC / 4) + 255) / 256), dim3(256), 0, stream>>>(part, bvec, out);
}

// Round 11
// 73.086 us; speedup vs baseline: 1.0011x; 1.0011x over previous
//
#include <hip/hip_runtime.h>
#include <math.h>

namespace {
constexpr int NB = 2048;      // batch
constexpr int NNODE = 6;      // nodes
constexpr int DD = 2048;      // feature dim
constexpr int HH = 1024;      // hidden
constexpr int CC = 200;       // classes
constexpr int K2 = 2 * DD;    // 4096 (concat dim)
constexpr int NPAD = 256;     // padded class dim
constexpr int ZS1 = 4;        // split-K for g1 (K per z = 256)
constexpr int ZS2 = 16;       // split-K for gemm2 (K per z = 256)
constexpr float ALPHA_C = 0.015f;
constexpr float SCALE_C = 24.0f;
}

typedef __attribute__((ext_vector_type(8))) short bf16x8;
typedef __attribute__((ext_vector_type(4))) float f32x4;

static __device__ __forceinline__ unsigned short f2bf(float x) {
    union { float f; unsigned int u; } v; v.f = x;
    unsigned int r = v.u + 0x7FFFu + ((v.u >> 16) & 1u);  // RNE
    return (unsigned short)(r >> 16);
}

static __device__ __forceinline__ float bf2f(unsigned short u) {
    union { unsigned int i; float f; } v; v.i = ((unsigned int)u) << 16;
    return v.f;
}

static __device__ __forceinline__ unsigned pack2(float a, float b) {
    return (unsigned)f2bf(a) | ((unsigned)f2bf(b) << 16);
}

// ---------------------------------------------------------------------------
// Wave-parallel node weights (lane u*8+v computes one exp+sqrt); lane v==0
// holds s[u] after the 8-lane row reduce.
// ---------------------------------------------------------------------------
static __device__ __forceinline__ float compute_s_lane(const float* __restrict__ cdds,
                                                       int b, int* u_out) {
    const int lane = threadIdx.x & 63;
    const int u = lane >> 3;      // 0..7
    const int v = lane & 7;       // 0..7
    *u_out = u;
    const float* cd = cdds + (size_t)b * 36;
    float w = 0.f;
    const bool valid = (u < 6) & (v < 6) & (u != v);
    if (u < 6 && v < 6 && u != v) {
        float cyu = (cd[u * 6 + 1] + cd[u * 6 + 3]) * 0.5f;
        float cxu = (cd[u * 6 + 2] + cd[u * 6 + 4]) * 0.5f;
        float cyv = (cd[v * 6 + 1] + cd[v * 6 + 3]) * 0.5f;
        float cxv = (cd[v * 6 + 2] + cd[v * 6 + 4]) * 0.5f;
        float dx = cxu - cxv, dy = cyu - cyv;
        w = expf(-ALPHA_C * sqrtf(dx * dx + dy * dy));
    }
    float s = w;
#pragma unroll
    for (int m = 32; m >= 1; m >>= 1) s += __shfl_xor(s, m);
    float mean = s * (1.f / 30.f);
    float tt = valid ? fmaxf(w - mean, 0.f) : 0.f;
    tt += __shfl_xor(tt, 1);
    tt += __shfl_xor(tt, 2);
    tt += __shfl_xor(tt, 4);
    return SCALE_C * tt * 0.2f;   // s[u] for this lane's row u
}

// ---------------------------------------------------------------------------
// k_small: blocks [0,64):   cls_w -> cls_wT bf16 [256][1024] (transposed,pad)
//          blocks [64,89):  bvec[c] = fc_b @ cls_w + cls_b
//          blocks [89,601): sbuf[b][u] node weights (one b per wave)
// ---------------------------------------------------------------------------
__global__ __launch_bounds__(256) void k_small(const float* __restrict__ cls_w,
                                               const float* __restrict__ fc_b,
                                               const float* __restrict__ cls_b,
                                               const float* __restrict__ cdds,
                                               unsigned short* __restrict__ cls_wT,
                                               float* __restrict__ bvec,
                                               float* __restrict__ sbuf)
{
    __shared__ float sm[64 * 65];
    const int bx = blockIdx.x;
    const int t = threadIdx.x;
    if (bx >= 89) {
        const int b = (bx - 89) * 4 + (t >> 6);
        int u;
        float su = compute_s_lane(cdds, b, &u);
        if ((t & 7) == 0 && u < 6) sbuf[b * 6 + u] = su;
        return;
    }
    if (bx >= 64) {
        const int bb = bx - 64;           // 0..24
        float* red = sm;
        int c8 = t & 7;
        int hs = t >> 3;
        int c = bb * 8 + c8;              // < 200
        float acc = 0.f;
        for (int h = hs; h < HH; h += 32)
            acc += fc_b[h] * cls_w[(size_t)h * CC + c];
        red[t] = acc;
        __syncthreads();
        for (int s = 128; s >= 8; s >>= 1) {
            if (t < s) red[t] += red[t + s];
            __syncthreads();
        }
        if (t < 8) bvec[c] = red[t] + cls_b[c];
        return;
    }
    const int kt = bx & 15;
    const int nt = bx >> 4;
#pragma unroll
    for (int c = 0; c < 4; ++c) {
        int i = t + c * 256;
        int kr = i >> 4;
        int n4 = (i & 15) << 2;
        int gn = nt * 64 + n4;
        const float* sp = cls_w + (size_t)(kt * 64 + kr) * CC + gn;
        float4 v = {0.f, 0.f, 0.f, 0.f};
        if (gn + 3 < CC) {
            v = *(const float4*)sp;
        } else {
            if (gn + 0 < CC) v.x = sp[0];
            if (gn + 1 < CC) v.y = sp[1];
            if (gn + 2 < CC) v.z = sp[2];
            if (gn + 3 < CC) v.w = sp[3];
        }
        sm[kr * 65 + n4 + 0] = v.x; sm[kr * 65 + n4 + 1] = v.y;
        sm[kr * 65 + n4 + 2] = v.z; sm[kr * 65 + n4 + 3] = v.w;
    }
    __syncthreads();
#pragma unroll
    for (int c = 0; c < 4; ++c) {
        int i = t + c * 256;
        int nr = i >> 4;
        int k4 = (i & 15) << 2;
        ushort4 o;
        o.x = f2bf(sm[(k4 + 0) * 65 + nr]);
        o.y = f2bf(sm[(k4 + 1) * 65 + nr]);
        o.z = f2bf(sm[(k4 + 2) * 65 + nr]);
        o.w = f2bf(sm[(k4 + 3) * 65 + nr]);
        *(ushort4*)(cls_wT + (size_t)(nt * 64 + nr) * HH + kt * 64 + k4) = o;
    }
}

// ---------------------------------------------------------------------------
// k_g1: partM[z][4096][256] = fc_w[:, z-slice] @ cls_w[z-slice, :]  (f32)
// grid (128, 4): tile 32m x 256n, K per z = 256. 512 blocks.
// ---------------------------------------------------------------------------
__global__ __launch_bounds__(256) void k_g1(const float* __restrict__ fc_w,
                                            const unsigned short* __restrict__ Bt,
                                            float* __restrict__ partM)
{
    __shared__ short As[32][72];
    __shared__ short Bs[256][72];
    const int t = threadIdx.x;
    const int lane = t & 63;
    const int wid = t >> 6;
    const int bm = blockIdx.x * 32;
    const int z = blockIdx.y;
    const int kbase = z * (HH / ZS1);   // 256

    f32x4 acc[2][4] = {};

    for (int k0 = kbase; k0 < kbase + HH / ZS1; k0 += 64) {
#pragma unroll
        for (int c = 0; c < 2; ++c) {
            int i = t + c * 256;
            int row = i >> 4;              // 0..31
            int k4 = (i & 15) << 2;
            float4 v = *(const float4*)(fc_w + (size_t)(bm + row) * HH + k0 + k4);
            ushort4 o;
            o.x = f2bf(v.x); o.y = f2bf(v.y); o.z = f2bf(v.z); o.w = f2bf(v.w);
            *(ushort4*)&As[row][k4] = o;
        }
#pragma unroll
        for (int c = 0; c < 8; ++c) {
            int i = t + c * 256;
            int n = i >> 3;                // 0..255
            int k8 = (i & 7) << 3;
            *(uint4*)&Bs[n][k8] =
                *(const uint4*)(Bt + (size_t)n * HH + k0 + k8);
        }
        __syncthreads();
#pragma unroll
        for (int ks = 0; ks < 2; ++ks) {
            int kk = ks * 32 + ((lane >> 4) << 3);
            int ar = lane & 15;
            bf16x8 a0 = *(const bf16x8*)&As[ar][kk];
            bf16x8 a1 = *(const bf16x8*)&As[16 + ar][kk];
#pragma unroll
            for (int fn = 0; fn < 4; ++fn) {
                bf16x8 b = *(const bf16x8*)&Bs[wid * 64 + fn * 16 + ar][kk];
                acc[0][fn] = __builtin_amdgcn_mfma_f32_16x16x32_bf16(a0, b, acc[0][fn], 0, 0, 0);
                acc[1][fn] = __builtin_amdgcn_mfma_f32_16x16x32_bf16(a1, b, acc[1][fn], 0, 0, 0);
            }
        }
        __syncthreads();
    }
#pragma unroll
    for (int fm = 0; fm < 2; ++fm)
#pragma unroll
        for (int fn = 0; fn < 4; ++fn) {
            int gm0 = bm + fm * 16 + ((lane >> 4) << 2);
            int gn = wid * 64 + fn * 16 + (lane & 15);
#pragma unroll
            for (int r = 0; r < 4; ++r)
                partM[((size_t)z * K2 + gm0 + r) * NPAD + gn] = acc[fm][fn][r];
        }
}

// ---------------------------------------------------------------------------
// k_pq: 512 blocks x 4 batches, 2-deep register pipeline, zero LDS.
// Thread t owns d=[8t,8t+8) of every row. 24 loads in flight steady-state.
// ---------------------------------------------------------------------------
struct Rows { float4 r[12]; };

static __device__ __forceinline__ Rows load_rows(const float* __restrict__ base) {
    Rows x;
#pragma unroll
    for (int u = 0; u < NNODE; ++u) {
        x.r[2 * u + 0] = *(const float4*)(base + (size_t)u * DD);
        x.r[2 * u + 1] = *(const float4*)(base + (size_t)u * DD + 4);
    }
    return x;
}

static __device__ __forceinline__ void compute_store(const Rows& x,
                                                     const float* __restrict__ sb,
                                                     unsigned short* __restrict__ o,
                                                     int d) {
    float s0 = sb[0], s1 = sb[1], s2 = sb[2], s3 = sb[3], s4 = sb[4], s5 = sb[5];
    float4 q0, q1, p0 = {0, 0, 0, 0}, p1 = {0, 0, 0, 0};
    q0.x = x.r[0].x + x.r[2].x + x.r[4].x + x.r[6].x + x.r[8].x + x.r[10].x;
    q0.y = x.r[0].y + x.r[2].y + x.r[4].y + x.r[6].y + x.r[8].y + x.r[10].y;
    q0.z = x.r[0].z + x.r[2].z + x.r[4].z + x.r[6].z + x.r[8].z + x.r[10].z;
    q0.w = x.r[0].w + x.r[2].w + x.r[4].w + x.r[6].w + x.r[8].w + x.r[10].w;
    q1.x = x.r[1].x + x.r[3].x + x.r[5].x + x.r[7].x + x.r[9].x + x.r[11].x;
    q1.y = x.r[1].y + x.r[3].y + x.r[5].y + x.r[7].y + x.r[9].y + x.r[11].y;
    q1.z = x.r[1].z + x.r[3].z + x.r[5].z + x.r[7].z + x.r[9].z + x.r[11].z;
    q1.w = x.r[1].w + x.r[3].w + x.r[5].w + x.r[7].w + x.r[9].w + x.r[11].w;
    const float sv[6] = {s0, s1, s2, s3, s4, s5};
#pragma unroll
    for (int u = 0; u < 6; ++u) {
        float s = sv[u];
        p0.x = fmaf(s, x.r[2 * u].x, p0.x); p0.y = fmaf(s, x.r[2 * u].y, p0.y);
        p0.z = fmaf(s, x.r[2 * u].z, p0.z); p0.w = fmaf(s, x.r[2 * u].w, p0.w);
        p1.x = fmaf(s, x.r[2 * u + 1].x, p1.x); p1.y = fmaf(s, x.r[2 * u + 1].y, p1.y);
        p1.z = fmaf(s, x.r[2 * u + 1].z, p1.z); p1.w = fmaf(s, x.r[2 * u + 1].w, p1.w);
    }
    uint4 po, qo;
    po.x = pack2(p0.x, p0.y); po.y = pack2(p0.z, p0.w);
    po.z = pack2(p1.x, p1.y); po.w = pack2(p1.z, p1.w);
    qo.x = pack2(q0.x, q0.y); qo.y = pack2(q0.z, q0.w);
    qo.z = pack2(q1.x, q1.y); qo.w = pack2(q1.z, q1.w);
    *(uint4*)(o + d) = po;
    *(uint4*)(o + DD + d) = qo;
}

__global__ __launch_bounds__(256, 1) void k_pq(const float* __restrict__ pf,
                                               const float* __restrict__ sbuf,
                                               unsigned short* __restrict__ pq)
{
    const int t = threadIdx.x;
    const int d = t << 3;                 // 8 floats per thread
    const int b0 = blockIdx.x * 4;
    const float* base = pf + (size_t)b0 * NNODE * DD + d;

    Rows A = load_rows(base);
    Rows B = load_rows(base + 1 * NNODE * DD);
    compute_store(A, sbuf + (b0 + 0) * 6, pq + (size_t)(b0 + 0) * K2, d);
    A = load_rows(base + 2 * NNODE * DD);
    compute_store(B, sbuf + (b0 + 1) * 6, pq + (size_t)(b0 + 1) * K2, d);
    B = load_rows(base + 3 * NNODE * DD);
    compute_store(A, sbuf + (b0 + 2) * 6, pq + (size_t)(b0 + 2) * K2, d);
    compute_store(B, sbuf + (b0 + 3) * 6, pq + (size_t)(b0 + 3) * K2, d);
}

// ---------------------------------------------------------------------------
// k_red: Mt[n][m] bf16 = sum_z partM[z][m][n] (64x64 LDS transpose tiles)
// ---------------------------------------------------------------------------
__global__ __launch_bounds__(256) void k_red(const float* __restrict__ partM,
                                             unsigned short* __restrict__ Mt)
{
    __shared__ float sm[64][69];
    const int bx = blockIdx.x;
    const int t = threadIdx.x;
    const int bm = (bx >> 2) * 64;        // m-tile (4096)
    const int bn = (bx & 3) * 64;         // n-tile (256)
#pragma unroll
    for (int c = 0; c < 4; ++c) {
        int i = t + c * 256;
        int mr = i >> 4;                  // 0..63
        int n4 = (i & 15) << 2;
        float4 s = {0.f, 0.f, 0.f, 0.f};
#pragma unroll
        for (int z = 0; z < ZS1; ++z) {
            float4 v = *(const float4*)(partM +
                ((size_t)z * K2 + bm + mr) * NPAD + bn + n4);
            s.x += v.x; s.y += v.y; s.z += v.z; s.w += v.w;
        }
        sm[mr][n4 + 0] = s.x; sm[mr][n4 + 1] = s.y;
        sm[mr][n4 + 2] = s.z; sm[mr][n4 + 3] = s.w;
    }
    __syncthreads();
#pragma unroll
    for (int c = 0; c < 4; ++c) {
        int i = t + c * 256;
        int nr = i >> 4;                  // 0..63
        int m4 = (i & 15) << 2;
        ushort4 o;
        o.x = f2bf(sm[m4 + 0][nr]);
        o.y = f2bf(sm[m4 + 1][nr]);
        o.z = f2bf(sm[m4 + 2][nr]);
        o.w = f2bf(sm[m4 + 3][nr]);
        *(ushort4*)(Mt + (size_t)(bn + nr) * K2 + bm + m4) = o;
    }
}

// ---------------------------------------------------------------------------
// GEMM2: part[z][2048][256] bf16 = pq @ Mt^T partial (split-K=16)
// grid (32, 16) = 512 blocks. Block 64m x 256n; wave tile 64m x 64n.
// ---------------------------------------------------------------------------
__global__ __launch_bounds__(256) void k_gemm2(const unsigned short* __restrict__ A,
                                               const unsigned short* __restrict__ Bt,
                                               unsigned short* __restrict__ part)
{
    __shared__ short As[64][72];    // 9.2 KB
    __shared__ short Bs[256][72];   // 36.9 KB
    const int t = threadIdx.x;
    const int lane = t & 63;
    const int wid = t >> 6;         // n-strip
    const int bm = blockIdx.x * 64;
    const int z = blockIdx.y;
    const int kbase = z * (K2 / ZS2);   // 256 per z

    f32x4 acc[4][4] = {};

    for (int k0 = kbase; k0 < kbase + K2 / ZS2; k0 += 64) {
#pragma unroll
        for (int c = 0; c < 2; ++c) {
            int i = t + c * 256;
            int row = i >> 3;
            int k8 = (i & 7) << 3;
            *(uint4*)&As[row][k8] =
                *(const uint4*)(A + (size_t)(bm + row) * K2 + k0 + k8);
        }
#pragma unroll
        for (int c = 0; c < 8; ++c) {
            int i = t + c * 256;
            int n = i >> 3;
            int k8 = (i & 7) << 3;
            *(uint4*)&Bs[n][k8] =
                *(const uint4*)(Bt + (size_t)n * K2 + k0 + k8);
        }
        __syncthreads();
#pragma unroll
        for (int ks = 0; ks < 2; ++ks) {
            int kk = ks * 32 + ((lane >> 4) << 3);
            int ar = lane & 15;
            bf16x8 a0 = *(const bf16x8*)&As[0 * 16 + ar][kk];
            bf16x8 a1 = *(const bf16x8*)&As[1 * 16 + ar][kk];
            bf16x8 a2 = *(const bf16x8*)&As[2 * 16 + ar][kk];
            bf16x8 a3 = *(const bf16x8*)&As[3 * 16 + ar][kk];
#pragma unroll
            for (int fn = 0; fn < 4; ++fn) {
                bf16x8 b = *(const bf16x8*)&Bs[wid * 64 + fn * 16 + ar][kk];
                acc[0][fn] = __builtin_amdgcn_mfma_f32_16x16x32_bf16(a0, b, acc[0][fn], 0, 0, 0);
                acc[1][fn] = __builtin_amdgcn_mfma_f32_16x16x32_bf16(a1, b, acc[1][fn], 0, 0, 0);
                acc[2][fn] = __builtin_amdgcn_mfma_f32_16x16x32_bf16(a2, b, acc[2][fn], 0, 0, 0);
                acc[3][fn] = __builtin_amdgcn_mfma_f32_16x16x32_bf16(a3, b, acc[3][fn], 0, 0, 0);
            }
        }
        __syncthreads();
    }
#pragma unroll
    for (int fm = 0; fm < 4; ++fm)
#pragma unroll
        for (int fn = 0; fn < 4; ++fn) {
            int gm0 = bm + fm * 16 + ((lane >> 4) << 2);
            int gn = wid * 64 + fn * 16 + (lane & 15);
#pragma unroll
            for (int r = 0; r < 4; ++r)
                part[((size_t)z * NB + gm0 + r) * NPAD + gn] = f2bf(acc[fm][fn][r]);
        }
}

// ---------------------------------------------------------------------------
// out[b,c0..c0+3] = (sum_z part[z][b][c]) / 6 + bvec[c]
// ---------------------------------------------------------------------------
__global__ __launch_bounds__(256) void k_combine(const unsigned short* __restrict__ part,
                                                 const float* __restrict__ bvec,
                                                 float* __restrict__ out)
{
    int idx = blockIdx.x * blockDim.x + threadIdx.x;   // NB * 50
    if (idx >= NB * (CC / 4)) return;
    int b = idx / (CC / 4);
    int c0 = (idx - b * (CC / 4)) << 2;
    float s0 = 0.f, s1 = 0.f, s2 = 0.f, s3 = 0.f;
#pragma unroll
    for (int z = 0; z < ZS2; ++z) {
        ushort4 v = *(const ushort4*)(part + ((size_t)z * NB + b) * NPAD + c0);
        s0 += bf2f(v.x); s1 += bf2f(v.y); s2 += bf2f(v.z); s3 += bf2f(v.w);
    }
    float4 o;
    o.x = s0 * (1.f / 6.f) + bvec[c0 + 0];
    o.y = s1 * (1.f / 6.f) + bvec[c0 + 1];
    o.z = s2 * (1.f / 6.f) + bvec[c0 + 2];
    o.w = s3 * (1.f / 6.f) + bvec[c0 + 3];
    *(float4*)(out + (size_t)b * CC + c0) = o;
}

// ---------------------------------------------------------------------------
extern "C" void kernel_launch(void* const* d_in, const int* in_sizes, int n_in,
                              void* d_out, int out_size, void* d_ws, size_t ws_size,
                              hipStream_t stream)
{
    const float* part_feats = (const float*)d_in[0];
    const float* cdds = (const float*)d_in[1];
    const float* fc_w = (const float*)d_in[2];   // (4096, 1024)
    const float* fc_b = (const float*)d_in[3];   // (1024,)
    const float* cls_w = (const float*)d_in[4];  // (1024, 200)
    const float* cls_b = (const float*)d_in[5];  // (200,)
    float* out = (float*)d_out;                  // (2048, 200)

    char* ws = (char*)d_ws;
    size_t off = 0;
    unsigned short* pq = (unsigned short*)(ws + off);     off += (size_t)NB * K2 * 2;         // 16.8 MB
    unsigned short* Mt = (unsigned short*)(ws + off);     off += (size_t)NPAD * K2 * 2;       // 2.1 MB
    unsigned short* cls_wT = (unsigned short*)(ws + off); off += (size_t)NPAD * HH * 2;       // 0.5 MB
    float* partM = (float*)(ws + off);                    off += (size_t)ZS1 * K2 * NPAD * 4; // 16.8 MB
    unsigned short* part = (unsigned short*)(ws + off);   off += (size_t)ZS2 * NB * NPAD * 2; // 16.8 MB
    float* bvec = (float*)(ws + off);                     off += 256 * 4;
    float* sbuf = (float*)(ws + off);                     off += (size_t)NB * NNODE * 4;

    // 1. cls_w -> cls_wT bf16 + bvec + node-weight table sbuf
    k_small<<<dim3(64 + 25 + NB / 4), dim3(256), 0, stream>>>(
        cls_w, fc_b, cls_b, cdds, cls_wT, bvec, sbuf);
    // 2. fc_w @ cls_wT partials, split-K=4
    k_g1<<<dim3(K2 / 32, ZS1), dim3(256), 0, stream>>>(fc_w, cls_wT, partM);
    // 3. pq stream: 512 blocks x 4 batches, 2-deep register pipeline
    k_pq<<<dim3(NB / 4), dim3(256), 0, stream>>>(part_feats, sbuf, pq);
    // 4. reduce partM -> Mt bf16
    k_red<<<dim3(256), dim3(256), 0, stream>>>(partM, Mt);
    // 5. pq @ Mt^T partials (bf16), split-K=16
    k_gemm2<<<dim3(NB / 64, ZS2), dim3(256), 0, stream>>>(pq, Mt, part);
    // 6. combine + scale + bias
    k_combine<<<dim3((NB * (CC / 4) + 255) / 256), dim3(256), 0, stream>>>(part, bvec, out);
}